// Round 2
// baseline (522.681 us; speedup 1.0000x reference)
//
#include <hip/hip_runtime.h>

#define NUM_BINS 15
#define NB 1024            // grid for partial kernel
#define NT 256             // threads per block
#define NROWS 32           // rows 0-15: packed cnt+acc (row 15 = dump); rows 16-31: conf (row 31 = dump)
#define NCOMP 45           // cnt[15] | acc[15] | conf[15] in ws

// Per-thread private LDS histogram column, comp-major rows of NT floats:
// bank(addr) = threadIdx.x % 32 -> always conflict-free regardless of bin.
// cnt & acc packed: val = 1.0 + label * 2^-10 (per-thread count <= 128 -> exact).
__device__ __forceinline__ void accum(float* hist, int t, float pv, int lv) {
    int bin = (int)ceilf(pv * 15.0f) - 1;   // matches jnp: ceil(p*15)-1 in fp32
    bin = min(max(bin, -1), 15);            // invalid (p<=0 -> <=-1, p>1 -> >=15)
    bin &= 15;                              // -1 -> 15 (dump row)
    float v0 = fmaf((float)lv, 0.0009765625f, 1.0f);
    atomicAdd(&hist[(bin << 8) + t], v0);          // ds_add_f32, row = bin
    atomicAdd(&hist[((bin + 16) << 8) + t], pv);   // ds_add_f32, row = bin+16 (offset:16384)
}

__global__ __launch_bounds__(NT) void ece_partial(
    const float* __restrict__ probs, const int* __restrict__ labels,
    float* __restrict__ ws, int n4)
{
    __shared__ float hist[NROWS * NT];   // 32 KB
    const int t = threadIdx.x;

    // zero LDS
    float4* h4 = (float4*)hist;
#pragma unroll
    for (int i = 0; i < (NROWS * NT / 4) / NT; ++i)
        h4[i * NT + t] = float4{0.f, 0.f, 0.f, 0.f};
    __syncthreads();

    const float4* __restrict__ p4 = (const float4*)probs;
    const int4*   __restrict__ l4 = (const int4*)labels;
    const int tid    = blockIdx.x * NT + t;
    const int stride = gridDim.x * NT;

    const int iters = n4 / stride;
#pragma unroll 4
    for (int k = 0; k < iters; ++k) {
        const int i = tid + k * stride;
        float4 p = p4[i];
        int4   l = l4[i];
        accum(hist, t, p.x, l.x);
        accum(hist, t, p.y, l.y);
        accum(hist, t, p.z, l.z);
        accum(hist, t, p.w, l.w);
    }
    {   // tail (n4 not divisible by stride)
        const int i = tid + iters * stride;
        if (i < n4) {
            float4 p = p4[i];
            int4   l = l4[i];
            accum(hist, t, p.x, l.x);
            accum(hist, t, p.y, l.y);
            accum(hist, t, p.z, l.z);
            accum(hist, t, p.w, l.w);
        }
    }
    __syncthreads();

    // Block reduction: thread t -> row r = t>>3 (0..31), strip s = t&7 (32 cols each).
    const int r = t >> 3, s = t & 7;
    const float4* rp4 = (const float4*)(hist + (r << 8) + (s << 5));
    if (r < 16) {
        // packed cnt+acc rows: unpack per cell (cell <= 128.125, exact)
        float csum = 0.f, asum = 0.f;
#pragma unroll
        for (int k = 0; k < 8; ++k) {
            float4 v = rp4[k];
            float c0 = floorf(v.x), c1 = floorf(v.y), c2 = floorf(v.z), c3 = floorf(v.w);
            csum += (c0 + c1) + (c2 + c3);
            asum += ((v.x - c0) + (v.y - c1)) + ((v.z - c2) + (v.w - c3));
        }
        asum *= 1024.f;
#pragma unroll
        for (int o = 4; o; o >>= 1) {
            csum += __shfl_down(csum, o);
            asum += __shfl_down(asum, o);
        }
        if (s == 0 && r < NUM_BINS) {
            ws[r * NB + blockIdx.x]              = csum;
            ws[(NUM_BINS + r) * NB + blockIdx.x] = asum;
        }
    } else {
        float fsum = 0.f;
#pragma unroll
        for (int k = 0; k < 8; ++k) {
            float4 v = rp4[k];
            fsum += (v.x + v.y) + (v.z + v.w);
        }
#pragma unroll
        for (int o = 4; o; o >>= 1) fsum += __shfl_down(fsum, o);
        const int b = r - 16;
        if (s == 0 && b < NUM_BINS)
            ws[(2 * NUM_BINS + b) * NB + blockIdx.x] = fsum;
    }
}

// Final: 16 waves, each reduces ~3 rows of 1024 partials via float4 loads.
__global__ __launch_bounds__(1024) void ece_final(
    const float* __restrict__ ws, float* __restrict__ out, float n)
{
    __shared__ float sums[NCOMP];
    const int wave = threadIdx.x >> 6;
    const int lane = threadIdx.x & 63;

    for (int c = wave; c < NCOMP; c += 16) {
        const float4* row4 = (const float4*)(ws + c * NB);
        float s = 0.f;
#pragma unroll
        for (int k = 0; k < NB / 256; ++k) {
            float4 v = row4[lane + (k << 6)];
            s += (v.x + v.y) + (v.z + v.w);
        }
#pragma unroll
        for (int o = 32; o; o >>= 1) s += __shfl_down(s, o);
        if (lane == 0) sums[c] = s;
    }
    __syncthreads();

    if (threadIdx.x == 0) {
        float ece = 0.f;
#pragma unroll
        for (int b = 0; b < NUM_BINS; ++b) {
            float cnt = sums[b];
            float acc = sums[NUM_BINS + b];
            float cf  = sums[2 * NUM_BINS + b];
            float denom = fmaxf(cnt, 1.f);
            ece += (cnt / n) * fabsf(acc / denom - cf / denom);
        }
        out[0] = ece;
    }
}

extern "C" void kernel_launch(void* const* d_in, const int* in_sizes, int n_in,
                              void* d_out, int out_size, void* d_ws, size_t ws_size,
                              hipStream_t stream)
{
    const float* probs  = (const float*)d_in[0];
    const int*   labels = (const int*)d_in[1];
    const int n = in_sizes[0];   // 33,554,432 (divisible by 4)

    ece_partial<<<NB, NT, 0, stream>>>(probs, labels, (float*)d_ws, n / 4);
    ece_final<<<1, 1024, 0, stream>>>((const float*)d_ws, (float*)d_out, (float)n);
}

// Round 3
// 278.818 us; speedup vs baseline: 1.8746x; 1.8746x over previous
//
#include <hip/hip_runtime.h>

#define NUM_BINS 15
#define NB 1024            // grid for partial kernel (4 blocks/CU exactly)
#define NT 256             // threads per block
#define NCOMP 45           // ws rows: cnt[15] | acc[15] | conf[15]

// Private per-thread LDS histogram column: cell[bin][t] = float2{cnt+acc/1024, conf}.
// Thread t owns column t of every row -> no races -> plain read/add/write (NO atomics).
// Row 15 is the dump row for invalid elements (p<=0 or p>1).
__global__ __launch_bounds__(NT) void ece_partial(
    const float* __restrict__ probs, const int* __restrict__ labels,
    float* __restrict__ ws, int n4)
{
    __shared__ float2 hist[16 * NT];   // 32 KB
    const int t = threadIdx.x;

#pragma unroll
    for (int i = 0; i < 16; ++i) hist[i * NT + t] = float2{0.f, 0.f};
    __syncthreads();

    const float4* __restrict__ p4 = (const float4*)probs;
    const int4*   __restrict__ l4 = (const int4*)labels;
    const int tid    = blockIdx.x * NT + t;
    const int stride = NB * NT;

    const int iters = n4 / stride;   // 8388608 / 262144 = 32
    for (int k = 0; k < iters; ++k) {
        const int i = tid + k * stride;
        float4 p = p4[i];
        int4   l = l4[i];
        float ps[4] = {p.x, p.y, p.z, p.w};
        int   ls[4] = {l.x, l.y, l.z, l.w};
#pragma unroll
        for (int e = 0; e < 4; ++e) {
            float pv = ps[e];
            // bin = ceil(p*15)-1 (fp32, matches jnp); invalid -> 15 (dump)
            int bin = (int)ceilf(pv * 15.0f) - 1;
            bin = (min(max(bin, -1), 15)) & 15;
            float2* cell = &hist[(bin << 8) + t];
            float2 v = *cell;                                   // ds_read_b64
            v.x += fmaf((float)ls[e], 0.0009765625f, 1.0f);     // cnt+acc/1024 (exact)
            v.y += pv;                                          // conf
            *cell = v;                                          // ds_write_b64
        }
    }
    {   // tail (generality; empty for N=2^25)
        const int i = tid + iters * stride;
        if (i < n4) {
            float4 p = p4[i];
            int4   l = l4[i];
            float ps[4] = {p.x, p.y, p.z, p.w};
            int   ls[4] = {l.x, l.y, l.z, l.w};
#pragma unroll
            for (int e = 0; e < 4; ++e) {
                float pv = ps[e];
                int bin = (int)ceilf(pv * 15.0f) - 1;
                bin = (min(max(bin, -1), 15)) & 15;
                float2* cell = &hist[(bin << 8) + t];
                float2 v = *cell;
                v.x += fmaf((float)ls[e], 0.0009765625f, 1.0f);
                v.y += pv;
                *cell = v;
            }
        }
    }
    __syncthreads();

    // Block reduce: row r = t>>4 (0..15), strip s = t&15 (16 cells each).
    const int r = t >> 4, s = t & 15;
    float csum = 0.f, asum = 0.f, fsum = 0.f;
#pragma unroll
    for (int k = 0; k < 16; ++k) {
        float2 v = hist[(r << 8) + (s << 4) + k];
        float c = floorf(v.x);           // cnt part (exact)
        csum += c;
        asum += v.x - c;                 // acc/1024 part (exact)
        fsum += v.y;
    }
    asum *= 1024.f;
#pragma unroll
    for (int o = 8; o; o >>= 1) {        // 16-lane groups are wave-aligned
        csum += __shfl_down(csum, o);
        asum += __shfl_down(asum, o);
        fsum += __shfl_down(fsum, o);
    }
    if (s == 0 && r < NUM_BINS) {
        ws[r * NB + blockIdx.x]                  = csum;
        ws[(NUM_BINS + r) * NB + blockIdx.x]     = asum;
        ws[(2 * NUM_BINS + r) * NB + blockIdx.x] = fsum;
    }
}

// Final: 16 waves reduce the [45][NB] partials (184 KB) and emit scalar ECE.
__global__ __launch_bounds__(1024) void ece_final(
    const float* __restrict__ ws, float* __restrict__ out, float n)
{
    __shared__ float sums[NCOMP];
    const int wave = threadIdx.x >> 6;
    const int lane = threadIdx.x & 63;

    for (int c = wave; c < NCOMP; c += 16) {
        const float4* row4 = (const float4*)(ws + c * NB);
        float s = 0.f;
#pragma unroll
        for (int k = 0; k < NB / 256; ++k) {
            float4 v = row4[lane + (k << 6)];
            s += (v.x + v.y) + (v.z + v.w);
        }
#pragma unroll
        for (int o = 32; o; o >>= 1) s += __shfl_down(s, o);
        if (lane == 0) sums[c] = s;
    }
    __syncthreads();

    if (threadIdx.x == 0) {
        float ece = 0.f;
#pragma unroll
        for (int b = 0; b < NUM_BINS; ++b) {
            float cnt = sums[b];
            float acc = sums[NUM_BINS + b];
            float cf  = sums[2 * NUM_BINS + b];
            float denom = fmaxf(cnt, 1.f);
            ece += (cnt / n) * fabsf(acc / denom - cf / denom);
        }
        out[0] = ece;
    }
}

extern "C" void kernel_launch(void* const* d_in, const int* in_sizes, int n_in,
                              void* d_out, int out_size, void* d_ws, size_t ws_size,
                              hipStream_t stream)
{
    const float* probs  = (const float*)d_in[0];
    const int*   labels = (const int*)d_in[1];
    const int n = in_sizes[0];   // 33,554,432

    ece_partial<<<NB, NT, 0, stream>>>(probs, labels, (float*)d_ws, n / 4);
    ece_final<<<1, 1024, 0, stream>>>((const float*)d_ws, (float*)d_out, (float)n);
}

// Round 4
// 278.368 us; speedup vs baseline: 1.8777x; 1.0016x over previous
//
#include <hip/hip_runtime.h>

#define NUM_BINS 15
#define NB 1024            // grid (4 blocks/CU)
#define NT 256             // threads per block
#define NCOMP 45           // ws rows: cnt[15] | acc[15] | conf[15]

// One uint32 carries all three stats for one element:
//   [31:24] label (acc), [23:16] 1 (cnt), [15:0] round((p - bin/15)*4096) (conf residual)
// Per-thread totals: cnt<=128, acc<=128, res<=128*273=34944 -> no field overflow.
#define INV15 0.066666667f

__device__ __forceinline__ unsigned pack_elem(float pv, int lv, int* bin_out) {
    // bin = clip(ceil(p*15)-1, ...); invalid (p<=0 or p>1) -> 15 (dump row, discarded)
    int bin = (int)ceilf(pv * 15.0f) - 1;
    bin = (min(max(bin, -1), 15)) & 15;
    *bin_out = bin;
    float res = fmaf((float)bin, -INV15, pv);          // p - bin/15  (>= ~-1ulp for valid bins)
    float x   = fmaf(res, 4096.0f, 0.5f);              // round-to-nearest via +0.5 + trunc
    unsigned rq = (unsigned)fmaxf(x, 0.0f);            // clamp negatives (dump-row garbage ok)
    return ((unsigned)lv << 24) + 0x10000u + rq;
}

__device__ __forceinline__ void process4(float4 p, int4 l,
                                         unsigned* hAt, unsigned* hBt, unsigned* reg) {
    int b0, b1, b2, b3;
    unsigned k0 = pack_elem(p.x, l.x, &b0);
    unsigned k1 = pack_elem(p.y, l.y, &b1);
    unsigned k2 = pack_elem(p.z, l.z, &b2);
    unsigned k3 = pack_elem(p.w, l.w, &b3);
    // elements 0,1 -> two independent LDS chains (separate arrays => no-alias)
    unsigned* ca = hAt + (b0 << 8);
    unsigned* cb = hBt + (b1 << 8);
    unsigned va = *ca;
    unsigned vb = *cb;
    *ca = va + k0;
    *cb = vb + k1;
    // elements 2,3 -> register histogram (16 uints, dump at 15)
#pragma unroll
    for (int b = 0; b < 16; ++b) {
        reg[b] += (b2 == b) ? k2 : 0u;
        reg[b] += (b3 == b) ? k3 : 0u;
    }
}

__global__ __launch_bounds__(NT) void ece_partial(
    const float* __restrict__ probs, const int* __restrict__ labels,
    float* __restrict__ ws, int n4)
{
    __shared__ unsigned hA[16 * NT];   // 16 KB, cell[bin][t]
    __shared__ unsigned hB[16 * NT];   // 16 KB
    const int t = threadIdx.x;

    uint4* a4 = (uint4*)hA;
    uint4* b4 = (uint4*)hB;
#pragma unroll
    for (int i = 0; i < 4; ++i) {
        a4[i * NT + t] = uint4{0u, 0u, 0u, 0u};
        b4[i * NT + t] = uint4{0u, 0u, 0u, 0u};
    }
    __syncthreads();

    unsigned reg[16];
#pragma unroll
    for (int b = 0; b < 16; ++b) reg[b] = 0u;

    const float4* __restrict__ p4 = (const float4*)probs;
    const int4*   __restrict__ l4 = (const int4*)labels;
    unsigned* hAt = hA + t;
    unsigned* hBt = hB + t;
    const int tid    = blockIdx.x * NT + t;
    const int stride = NB * NT;
    const int iters  = n4 / stride;   // 32 for N=2^25

#pragma unroll 2
    for (int k = 0; k < iters; ++k) {
        const int i = tid + k * stride;
        process4(p4[i], l4[i], hAt, hBt, reg);
    }
    {   // tail (empty for N=2^25; kept for generality)
        const int i = tid + iters * stride;
        if (i < n4) process4(p4[i], l4[i], hAt, hBt, reg);
    }

    // merge B + regs into A: thread t owns column t everywhere -> no sync needed yet
#pragma unroll
    for (int b = 0; b < 16; ++b)
        hA[(b << 8) + t] += hB[(b << 8) + t] + reg[b];
    __syncthreads();

    // cross-thread reduce: row r = t>>4 (0..15), strip s = t&15 (16 cells each)
    const int r = t >> 4, s = t & 15;
    float csum = 0.f, asum = 0.f, rsum = 0.f;
#pragma unroll
    for (int k = 0; k < 16; ++k) {
        unsigned v = hA[(r << 8) + (s << 4) + k];
        asum += (float)(v >> 24);
        csum += (float)((v >> 16) & 0xFFu);
        rsum += (float)(v & 0xFFFFu);
    }
#pragma unroll
    for (int o = 8; o; o >>= 1) {   // 16-lane strips are wave-aligned
        csum += __shfl_down(csum, o);
        asum += __shfl_down(asum, o);
        rsum += __shfl_down(rsum, o);
    }
    if (s == 0 && r < NUM_BINS) {
        // conf = cnt*(bin/15) + res/4096 (same INV15 constant as pack_elem)
        float conf = fmaf(csum, (float)r * INV15, rsum * 2.44140625e-4f);
        ws[r * NB + blockIdx.x]                  = csum;
        ws[(NUM_BINS + r) * NB + blockIdx.x]     = asum;
        ws[(2 * NUM_BINS + r) * NB + blockIdx.x] = conf;
    }
}

// Final: 16 waves reduce the [45][NB] partials (184 KB) and emit scalar ECE.
__global__ __launch_bounds__(1024) void ece_final(
    const float* __restrict__ ws, float* __restrict__ out, float n)
{
    __shared__ float sums[NCOMP];
    const int wave = threadIdx.x >> 6;
    const int lane = threadIdx.x & 63;

    for (int c = wave; c < NCOMP; c += 16) {
        const float4* row4 = (const float4*)(ws + c * NB);
        float s = 0.f;
#pragma unroll
        for (int k = 0; k < NB / 256; ++k) {
            float4 v = row4[lane + (k << 6)];
            s += (v.x + v.y) + (v.z + v.w);
        }
#pragma unroll
        for (int o = 32; o; o >>= 1) s += __shfl_down(s, o);
        if (lane == 0) sums[c] = s;
    }
    __syncthreads();

    if (threadIdx.x == 0) {
        float ece = 0.f;
#pragma unroll
        for (int b = 0; b < NUM_BINS; ++b) {
            float cnt = sums[b];
            float acc = sums[NUM_BINS + b];
            float cf  = sums[2 * NUM_BINS + b];
            float denom = fmaxf(cnt, 1.f);
            ece += (cnt / n) * fabsf(acc / denom - cf / denom);
        }
        out[0] = ece;
    }
}

extern "C" void kernel_launch(void* const* d_in, const int* in_sizes, int n_in,
                              void* d_out, int out_size, void* d_ws, size_t ws_size,
                              hipStream_t stream)
{
    const float* probs  = (const float*)d_in[0];
    const int*   labels = (const int*)d_in[1];
    const int n = in_sizes[0];   // 33,554,432

    ece_partial<<<NB, NT, 0, stream>>>(probs, labels, (float*)d_ws, n / 4);
    ece_final<<<1, 1024, 0, stream>>>((const float*)d_ws, (float*)d_out, (float)n);
}